// Round 5
// baseline (843.115 us; speedup 1.0000x reference)
//
#include <hip/hip_runtime.h>
#include <hip/hip_cooperative_groups.h>
#include <math.h>

namespace cg = cooperative_groups;

#define N_NODES 4096
#define DIM 256
#define GK 256
#define MWORDS 128
#define MAXNBR 192
#define MEGA_GRID 1024

typedef float f32x4 __attribute__((ext_vector_type(4)));
typedef short s16x8 __attribute__((ext_vector_type(8)));
typedef short s16x4 __attribute__((ext_vector_type(4)));

__device__ __forceinline__ unsigned short bf16_rne(float f) {
  unsigned int u = __float_as_uint(f);
  u += 0x7FFFu + ((u >> 16) & 1u);
  return (unsigned short)(u >> 16);
}

__device__ __forceinline__ void split_bf16(float f, short& hi, short& lo) {
  unsigned short h = bf16_rne(f);
  float hf = __uint_as_float(((unsigned int)h) << 16);
  hi = (short)h;
  lo = (short)bf16_rne(f - hf);
}

// LDS XOR swizzle for [64][64]-short tiles (pitch 64 shorts = 128B).
__device__ __forceinline__ int swz(int row, int col) {
  return row * 64 + (col ^ ((row & 7) << 3));
}

// ---------------------------------------------------------------------------
// Shared GEMM tile: C[m0:m0+64, n0:n0+64] = A[m0:,:256] @ Wt^T + bias.
// EPI 0: bias; 1: bias + ev*X; 2: A-side a'=relu(a*bnsc[k]+bnsh[k]).
// STATS_OUT: per-column sum/sumsq of stored C -> atomics into osum/osq.
// ---------------------------------------------------------------------------
template <int EPI, bool STATS_OUT>
__device__ __forceinline__ void gemm_tile(
    short* As_hi, short* As_lo, short* Bs_hi, short* Bs_lo, float* red,
    const float* __restrict__ A, const short* __restrict__ Wt_hi,
    const short* __restrict__ Wt_lo, const float* __restrict__ bias,
    float* __restrict__ C, int ldc, int m0, int n0,
    const float* __restrict__ X, float ev,
    const float* bnsc, const float* bnsh,
    float* __restrict__ osum, float* __restrict__ osq) {
  const int tid = threadIdx.x;
  const int lane = tid & 63;
  const int wave = tid >> 6;
  const int wr = wave >> 1, wc = wave & 1;
  const int l15 = lane & 15;
  const int lg = lane >> 4;

  f32x4 acc[2][2] = {};

  for (int kt = 0; kt < GK; kt += 64) {
    __syncthreads();
#pragma unroll
    for (int i = 0; i < 4; ++i) {
      const int row = (tid >> 4) + i * 16;
      const int kc = (tid & 15) * 4;
      float4 av = *(const float4*)(A + (size_t)(m0 + row) * GK + kt + kc);
      if (EPI == 2) {
        const float4 s4 = *(const float4*)&bnsc[kt + kc];
        const float4 h4 = *(const float4*)&bnsh[kt + kc];
        av.x = fmaxf(fmaf(av.x, s4.x, h4.x), 0.f);
        av.y = fmaxf(fmaf(av.y, s4.y, h4.y), 0.f);
        av.z = fmaxf(fmaf(av.z, s4.z, h4.z), 0.f);
        av.w = fmaxf(fmaf(av.w, s4.w, h4.w), 0.f);
      }
      short h0, l0, h1, l1, h2, l2, h3, l3;
      split_bf16(av.x, h0, l0);
      split_bf16(av.y, h1, l1);
      split_bf16(av.z, h2, l2);
      split_bf16(av.w, h3, l3);
      s16x4 hv = {h0, h1, h2, h3};
      s16x4 lv = {l0, l1, l2, l3};
      const int o = swz(row, kc);
      *(s16x4*)&As_hi[o] = hv;
      *(s16x4*)&As_lo[o] = lv;
    }
#pragma unroll
    for (int i = 0; i < 2; ++i) {
      const int row = (tid >> 3) + i * 32;
      const int kc = (tid & 7) * 8;
      s16x8 bh = *(const s16x8*)(Wt_hi + (size_t)(n0 + row) * GK + kt + kc);
      s16x8 bl = *(const s16x8*)(Wt_lo + (size_t)(n0 + row) * GK + kt + kc);
      const int o = swz(row, kc);
      *(s16x8*)&Bs_hi[o] = bh;
      *(s16x8*)&Bs_lo[o] = bl;
    }
    __syncthreads();
#pragma unroll
    for (int kk = 0; kk < 2; ++kk) {
      s16x8 ah[2], al[2], bh[2], bl[2];
#pragma unroll
      for (int f = 0; f < 2; ++f) {
        const int ao = swz(wr * 32 + f * 16 + l15, kk * 32 + lg * 8);
        const int bo = swz(wc * 32 + f * 16 + l15, kk * 32 + lg * 8);
        ah[f] = *(const s16x8*)&As_hi[ao];
        al[f] = *(const s16x8*)&As_lo[ao];
        bh[f] = *(const s16x8*)&Bs_hi[bo];
        bl[f] = *(const s16x8*)&Bs_lo[bo];
      }
#pragma unroll
      for (int fm = 0; fm < 2; ++fm)
#pragma unroll
        for (int fn = 0; fn < 2; ++fn) {
          acc[fm][fn] = __builtin_amdgcn_mfma_f32_16x16x32_bf16(ah[fm], bh[fn], acc[fm][fn], 0, 0, 0);
          acc[fm][fn] = __builtin_amdgcn_mfma_f32_16x16x32_bf16(ah[fm], bl[fn], acc[fm][fn], 0, 0, 0);
          acc[fm][fn] = __builtin_amdgcn_mfma_f32_16x16x32_bf16(al[fm], bh[fn], acc[fm][fn], 0, 0, 0);
        }
    }
  }

  float ps[2] = {0.f, 0.f}, pq[2] = {0.f, 0.f};
#pragma unroll
  for (int fm = 0; fm < 2; ++fm) {
    const int row0 = m0 + wr * 32 + fm * 16 + lg * 4;
#pragma unroll
    for (int fn = 0; fn < 2; ++fn) {
      const int col = n0 + wc * 32 + fn * 16 + l15;
      const float bb = bias[col];
#pragma unroll
      for (int j = 0; j < 4; ++j) {
        float v = acc[fm][fn][j] + bb;
        if (EPI == 1) v = fmaf(ev, X[(size_t)(row0 + j) * DIM + col], v);
        C[(size_t)(row0 + j) * ldc + col] = v;
        if (STATS_OUT) {
          ps[fn] += v;
          pq[fn] = fmaf(v, v, pq[fn]);
        }
      }
    }
  }
  if (STATS_OUT) {
    float* redS = red;        // [2][2][16]
    float* redQ = red + 64;
#pragma unroll
    for (int fn = 0; fn < 2; ++fn) {
      ps[fn] += __shfl_xor(ps[fn], 16);
      ps[fn] += __shfl_xor(ps[fn], 32);
      pq[fn] += __shfl_xor(pq[fn], 16);
      pq[fn] += __shfl_xor(pq[fn], 32);
    }
    if (wr == 1 && lane < 16) {
      redS[(wc * 2 + 0) * 16 + l15] = ps[0];
      redS[(wc * 2 + 1) * 16 + l15] = ps[1];
      redQ[(wc * 2 + 0) * 16 + l15] = pq[0];
      redQ[(wc * 2 + 1) * 16 + l15] = pq[1];
    }
    __syncthreads();
    if (wr == 0 && lane < 16) {
#pragma unroll
      for (int fn = 0; fn < 2; ++fn) {
        const int col = n0 + wc * 32 + fn * 16 + l15;
        atomicAdd(&osum[col], ps[fn] + redS[(wc * 2 + fn) * 16 + l15]);
        atomicAdd(&osq[col], pq[fn] + redQ[(wc * 2 + fn) * 16 + l15]);
      }
    }
    __syncthreads();
  }
}

// ---------------------------------------------------------------------------
struct Params {
  const float* x;
  const int* ei;
  int E;
  const float *wq, *wk, *wv, *wo, *w1, *w2;
  const float *bq, *bk, *bv, *bo, *b1, *b2;
  const float *g1, *be1, *g2, *be2;
  const float* eps;
  unsigned int* mask;
  short *wt_hi, *wt_lo;
  float *bqkv, *stats;
  float *qkv, *vagg, *a1, *h1, *h2, *out;
};

// ---------------------------------------------------------------------------
// Cooperative mega-kernel: whole pipeline, 6 grid syncs, zero extra launches.
// ---------------------------------------------------------------------------
__global__ void __launch_bounds__(256, 4) mega(Params p) {
  cg::grid_group grid = cg::this_grid();
  __shared__ __align__(16) char smraw[32768];
  __shared__ __align__(16) float bnsc[256], bnsh[256];
  __shared__ float red[128];
  short* As_hi = (short*)smraw;
  short* As_lo = As_hi + 4096;
  short* Bs_hi = As_lo + 4096;
  short* Bs_lo = Bs_hi + 4096;

  const int bid = blockIdx.x;
  const int tid = threadIdx.x;
  const int wave = tid >> 6;
  const int lane = tid & 63;

  // ================= Phase A: mask zero + weight split + stats/bqkv ========
  p.mask[bid * 512 + tid] = 0u;
  p.mask[bid * 512 + 256 + tid] = 0u;
  if (bid < 96) {  // weight hi/lo split, coalesced both sides via LDS transpose
    const int mat = bid >> 4;
    const int tile = bid & 15;
    const int ti = tile >> 2;  // k-block
    const int tj = tile & 3;   // n-block
    const float* src = (mat == 0) ? p.wq : (mat == 1) ? p.wk : (mat == 2) ? p.wv
                     : (mat == 3) ? p.wo : (mat == 4) ? p.w1 : p.w2;
    float(*tr)[65] = (float(*)[65])smraw;  // 64x65 f32 = 16.6 KB
#pragma unroll
    for (int q = 0; q < 16; ++q) {
      const int r = q * 4 + (tid >> 6);
      const int c = tid & 63;
      tr[r][c] = src[(size_t)(ti * 64 + r) * 256 + tj * 64 + c];
    }
    __syncthreads();
    const int nbase = (mat < 3) ? mat * 256 : 768 + (mat - 3) * 256;
#pragma unroll
    for (int q = 0; q < 16; ++q) {
      const int n = q * 4 + (tid >> 6);
      const int k = tid & 63;
      short hi, lo;
      split_bf16(tr[k][n], hi, lo);
      const size_t idx = (size_t)(nbase + tj * 64 + n) * GK + ti * 64 + k;
      p.wt_hi[idx] = hi;
      p.wt_lo[idx] = lo;
    }
  } else if (bid == 96) {
    p.stats[tid] = 0.f;
    p.stats[tid + 256] = 0.f;
    p.stats[tid + 512] = 0.f;
    p.stats[tid + 768] = 0.f;
  } else if (bid >= 97 && bid < 100) {
    const int mat = bid - 97;
    p.bqkv[mat * 256 + tid] = (mat == 0 ? p.bq : mat == 1 ? p.bk : p.bv)[tid];
  }
  grid.sync();

  // ================= Phase B: edge scatter + QKV GEMM ======================
  {
    const int e = bid * 256 + tid;
    if (e < p.E) {
      const int r = p.ei[e];
      const int c = p.ei[p.E + e];
      atomicOr(&p.mask[(size_t)r * MWORDS + (c >> 5)], 1u << (c & 31));
    }
  }
  if (bid < 768) {
    const int mt = bid & 63, nt = bid >> 6;
    gemm_tile<0, false>(As_hi, As_lo, Bs_hi, Bs_lo, red,
                        p.x, p.wt_hi, p.wt_lo, p.bqkv, p.qkv, 768,
                        mt * 64, nt * 64, nullptr, 0.f, nullptr, nullptr,
                        nullptr, nullptr);
  }
  grid.sync();

  // ================= Phase C: sparse attention (1 row / wave) ==============
  {
    int* nbr = (int*)smraw + wave * MAXNBR;
    const int r = bid * 4 + wave;
    const unsigned int* mrow = p.mask + (size_t)r * MWORDS;
    int total = 0;
#pragma unroll
    for (int round = 0; round < 2; ++round) {
      unsigned int w = mrow[round * 64 + lane];
      const int cnt = __popc(w);
      int pre = cnt;
#pragma unroll
      for (int off = 1; off < 64; off <<= 1) {
        int tt = __shfl_up(pre, off);
        if (lane >= off) pre += tt;
      }
      const int wtot = __shfl(pre, 63);
      pre -= cnt;
      int base = total + pre;
      while (w) {
        const int b = __ffs(w) - 1;
        w &= w - 1;
        nbr[base++] = (round * 64 + lane) * 32 + b;
      }
      total += wtot;
    }

    float4 q = *(const float4*)(p.qkv + (size_t)r * 768 + lane * 4);
    const float sc = 0.088388347648318447f;  // 1/sqrt(128)
    q.x *= sc; q.y *= sc; q.z *= sc; q.w *= sc;
    float4 acc = make_float4(0.f, 0.f, 0.f, 0.f);
    float m = -INFINITY, lsum = 0.f;

    for (int i = 0; i < total; i += 4) {
      int cs[4];
      float4 kf[4], vf[4];
      float d[4];
#pragma unroll
      for (int j = 0; j < 4; ++j) cs[j] = (i + j < total) ? nbr[i + j] : -1;
#pragma unroll
      for (int j = 0; j < 4; ++j) {
        const float* pp = p.qkv + (size_t)(cs[j] < 0 ? cs[0] : cs[j]) * 768 + lane * 4;
        kf[j] = *(const float4*)(pp + 256);
        vf[j] = *(const float4*)(pp + 512);
      }
#pragma unroll
      for (int j = 0; j < 4; ++j)
        d[j] = q.x * kf[j].x + q.y * kf[j].y + q.z * kf[j].z + q.w * kf[j].w;
#pragma unroll
      for (int s = 16; s >= 1; s >>= 1)
#pragma unroll
        for (int j = 0; j < 4; ++j) d[j] += __shfl_xor(d[j], s);
#pragma unroll
      for (int j = 1; j < 4; ++j)
        if (cs[j] < 0) d[j] = -INFINITY;
      float mnew = m;
#pragma unroll
      for (int j = 0; j < 4; ++j) mnew = fmaxf(mnew, d[j]);
      const float resc = __expf(m - mnew);
      float e[4], esum = 0.f;
#pragma unroll
      for (int j = 0; j < 4; ++j) {
        e[j] = __expf(d[j] - mnew);
        esum += e[j];
      }
      lsum = lsum * resc + esum;
      float ax = acc.x * resc, ay = acc.y * resc, az = acc.z * resc, aw = acc.w * resc;
#pragma unroll
      for (int j = 0; j < 4; ++j) {
        ax = fmaf(e[j], vf[j].x, ax);
        ay = fmaf(e[j], vf[j].y, ay);
        az = fmaf(e[j], vf[j].z, az);
        aw = fmaf(e[j], vf[j].w, aw);
      }
      acc.x = ax; acc.y = ay; acc.z = az; acc.w = aw;
      m = mnew;
    }
    const float inv = 1.f / lsum;
    float4 o = make_float4(acc.x * inv, acc.y * inv, acc.z * inv, acc.w * inv);
    *(float4*)(p.vagg + (size_t)r * DIM + lane * 4) = o;
  }
  grid.sync();

  // ================= Phase D: out-projection + eps*x =======================
  if (bid < 256) {
    const float ev = p.eps[0];
    gemm_tile<1, false>(As_hi, As_lo, Bs_hi, Bs_lo, red,
                        p.vagg, p.wt_hi + (size_t)768 * GK, p.wt_lo + (size_t)768 * GK,
                        p.bo, p.a1, DIM, (bid >> 2) * 64, (bid & 3) * 64,
                        p.x, ev, nullptr, nullptr, nullptr, nullptr);
  }
  grid.sync();

  // ================= Phase E: MLP1 + BN1 stats =============================
  if (bid < 256) {
    gemm_tile<0, true>(As_hi, As_lo, Bs_hi, Bs_lo, red,
                       p.a1, p.wt_hi + (size_t)1024 * GK, p.wt_lo + (size_t)1024 * GK,
                       p.b1, p.h1, DIM, (bid >> 2) * 64, (bid & 3) * 64,
                       nullptr, 0.f, nullptr, nullptr,
                       p.stats, p.stats + 256);
  }
  grid.sync();

  // ================= Phase F: BN1 finalize + MLP2 + BN2 stats ==============
  if (bid < 256) {
    const float invn = 1.f / (float)N_NODES;
    const float mu = p.stats[tid] * invn;
    const float var = p.stats[tid + 256] * invn - mu * mu;
    const float s = p.g1[tid] * rsqrtf(var + 1e-5f);
    bnsc[tid] = s;
    bnsh[tid] = fmaf(-mu, s, p.be1[tid]);
    gemm_tile<2, true>(As_hi, As_lo, Bs_hi, Bs_lo, red,
                       p.h1, p.wt_hi + (size_t)1280 * GK, p.wt_lo + (size_t)1280 * GK,
                       p.b2, p.h2, DIM, (bid >> 2) * 64, (bid & 3) * 64,
                       nullptr, 0.f, bnsc, bnsh,
                       p.stats + 512, p.stats + 768);
  }
  grid.sync();

  // ================= Phase G: BN2 finalize + apply + ReLU ==================
  {
    const int i = bid * 256 + tid;  // float4 index, exactly N*DIM/4
    const int c0 = (i * 4) & (DIM - 1);
    const float invn = 1.f / (float)N_NODES;
    const float4 s4 = *(const float4*)&p.stats[512 + c0];
    const float4 q4 = *(const float4*)&p.stats[768 + c0];
    const float4 g4 = *(const float4*)&p.g2[c0];
    const float4 b4 = *(const float4*)&p.be2[c0];
    float scl[4], shf[4];
#pragma unroll
    for (int j = 0; j < 4; ++j) {
      const float mu = ((const float*)&s4)[j] * invn;
      const float var = ((const float*)&q4)[j] * invn - mu * mu;
      const float s = ((const float*)&g4)[j] * rsqrtf(var + 1e-5f);
      scl[j] = s;
      shf[j] = fmaf(-mu, s, ((const float*)&b4)[j]);
    }
    const float4 h = ((const float4*)p.h2)[i];
    float4 o;
    o.x = fmaxf(fmaf(h.x, scl[0], shf[0]), 0.f);
    o.y = fmaxf(fmaf(h.y, scl[1], shf[1]), 0.f);
    o.z = fmaxf(fmaf(h.z, scl[2], shf[2]), 0.f);
    o.w = fmaxf(fmaf(h.w, scl[3], shf[3]), 0.f);
    ((float4*)p.out)[i] = o;
  }
}

// ===========================================================================
// Fallback path (round-4 proven kernels) in case cooperative launch is
// rejected under graph capture.
// ===========================================================================
__global__ void fb_prep(const int* __restrict__ ei, int E, int nmb,
                        unsigned int* __restrict__ mask,
                        const float* __restrict__ wq, const float* __restrict__ wk,
                        const float* __restrict__ wv, const float* __restrict__ wo,
                        const float* __restrict__ w1, const float* __restrict__ w2,
                        const float* __restrict__ bq, const float* __restrict__ bk,
                        const float* __restrict__ bv,
                        short* __restrict__ wt_hi, short* __restrict__ wt_lo,
                        float* __restrict__ bqkv, float* __restrict__ stats) {
  const int b = blockIdx.x;
  const int t = threadIdx.x;
  if (b < nmb) {
    const int e = b * 256 + t;
    if (e < E) {
      const int r = ei[e];
      const int c = ei[E + e];
      atomicOr(&mask[(size_t)r * MWORDS + (c >> 5)], 1u << (c & 31));
    }
    return;
  }
  const int b2 = b - nmb;
  if (b2 < 1536) {
    const int mat = b2 >> 8;
    const int n = b2 & 255;
    const float* src = (mat == 0) ? wq : (mat == 1) ? wk : (mat == 2) ? wv
                     : (mat == 3) ? wo : (mat == 4) ? w1 : w2;
    const float v = src[(size_t)t * 256 + n];
    short hi, lo;
    split_bf16(v, hi, lo);
    const int nbase = (mat < 3) ? mat * 256 : 768 + (mat - 3) * 256;
    const size_t idx = (size_t)(nbase + n) * GK + t;
    wt_hi[idx] = hi;
    wt_lo[idx] = lo;
    if (t == 0 && mat < 3)
      bqkv[mat * 256 + n] = (mat == 0 ? bq : mat == 1 ? bk : bv)[n];
    return;
  }
  stats[t] = 0.f;
  stats[t + 256] = 0.f;
  stats[t + 512] = 0.f;
  stats[t + 768] = 0.f;
}

template <int EPI, bool BN_IN, bool STATS_OUT>
__launch_bounds__(256)
__global__ void fb_gemm(const float* __restrict__ A,
                        const short* __restrict__ Wt_hi,
                        const short* __restrict__ Wt_lo,
                        const float* __restrict__ bias,
                        float* __restrict__ C, int ldc,
                        const float* __restrict__ X,
                        const float* __restrict__ epsp,
                        const float* __restrict__ bnsum,
                        const float* __restrict__ bnsq,
                        const float* __restrict__ bng,
                        const float* __restrict__ bnbe,
                        float* __restrict__ osum,
                        float* __restrict__ osq) {
  __shared__ __align__(16) char smraw[32768];
  __shared__ __align__(16) float bnsc[256], bnsh[256];
  __shared__ float red[128];
  short* As_hi = (short*)smraw;
  short* As_lo = As_hi + 4096;
  short* Bs_hi = As_lo + 4096;
  short* Bs_lo = Bs_hi + 4096;
  const int tid = threadIdx.x;
  if (BN_IN) {
    const float invn = 1.f / (float)N_NODES;
    const float mu = bnsum[tid] * invn;
    const float var = bnsq[tid] * invn - mu * mu;
    const float s = bng[tid] * rsqrtf(var + 1e-5f);
    bnsc[tid] = s;
    bnsh[tid] = fmaf(-mu, s, bnbe[tid]);
  }
  const float ev = (EPI == 1) ? epsp[0] : 0.f;
  gemm_tile<EPI, STATS_OUT>(As_hi, As_lo, Bs_hi, Bs_lo, red,
                            A, Wt_hi, Wt_lo, bias, C, ldc,
                            blockIdx.y * 64, blockIdx.x * 64,
                            X, ev, bnsc, bnsh, osum, osq);
}

__launch_bounds__(256)
__global__ void fb_attn(const float* __restrict__ qkv,
                        const unsigned int* __restrict__ mask,
                        float* __restrict__ vagg) {
  __shared__ int nbr[4][MAXNBR];
  const int wave = threadIdx.x >> 6;
  const int lane = threadIdx.x & 63;
  const int r = blockIdx.x * 4 + wave;
  const unsigned int* mrow = mask + (size_t)r * MWORDS;
  int total = 0;
#pragma unroll
  for (int round = 0; round < 2; ++round) {
    unsigned int w = mrow[round * 64 + lane];
    const int cnt = __popc(w);
    int pre = cnt;
#pragma unroll
    for (int off = 1; off < 64; off <<= 1) {
      int tt = __shfl_up(pre, off);
      if (lane >= off) pre += tt;
    }
    const int wtot = __shfl(pre, 63);
    pre -= cnt;
    int base = total + pre;
    while (w) {
      const int b = __ffs(w) - 1;
      w &= w - 1;
      nbr[wave][base++] = (round * 64 + lane) * 32 + b;
    }
    total += wtot;
  }
  float4 q = *(const float4*)(qkv + (size_t)r * 768 + lane * 4);
  const float sc = 0.088388347648318447f;
  q.x *= sc; q.y *= sc; q.z *= sc; q.w *= sc;
  float4 acc = make_float4(0.f, 0.f, 0.f, 0.f);
  float m = -INFINITY, lsum = 0.f;
  const int* nb = nbr[wave];
  for (int i = 0; i < total; i += 8) {
    int cs[8];
    float4 kf[8], vf[8];
    float d[8];
#pragma unroll
    for (int j = 0; j < 8; ++j) cs[j] = (i + j < total) ? nb[i + j] : -1;
#pragma unroll
    for (int j = 0; j < 8; ++j) {
      const float* pp = qkv + (size_t)(cs[j] < 0 ? cs[0] : cs[j]) * 768 + lane * 4;
      kf[j] = *(const float4*)(pp + 256);
      vf[j] = *(const float4*)(pp + 512);
    }
#pragma unroll
    for (int j = 0; j < 8; ++j)
      d[j] = q.x * kf[j].x + q.y * kf[j].y + q.z * kf[j].z + q.w * kf[j].w;
#pragma unroll
    for (int s = 16; s >= 1; s >>= 1)
#pragma unroll
      for (int j = 0; j < 8; ++j) d[j] += __shfl_xor(d[j], s);
#pragma unroll
    for (int j = 1; j < 8; ++j)
      if (cs[j] < 0) d[j] = -INFINITY;
    float mnew = m;
#pragma unroll
    for (int j = 0; j < 8; ++j) mnew = fmaxf(mnew, d[j]);
    const float resc = __expf(m - mnew);
    float e[8], esum = 0.f;
#pragma unroll
    for (int j = 0; j < 8; ++j) {
      e[j] = __expf(d[j] - mnew);
      esum += e[j];
    }
    lsum = lsum * resc + esum;
    float ax = acc.x * resc, ay = acc.y * resc, az = acc.z * resc, aw = acc.w * resc;
#pragma unroll
    for (int j = 0; j < 8; ++j) {
      ax = fmaf(e[j], vf[j].x, ax);
      ay = fmaf(e[j], vf[j].y, ay);
      az = fmaf(e[j], vf[j].z, az);
      aw = fmaf(e[j], vf[j].w, aw);
    }
    acc.x = ax; acc.y = ay; acc.z = az; acc.w = aw;
    m = mnew;
  }
  const float inv = 1.f / lsum;
  float4 o = make_float4(acc.x * inv, acc.y * inv, acc.z * inv, acc.w * inv);
  *(float4*)(vagg + (size_t)r * DIM + lane * 4) = o;
}

__launch_bounds__(256)
__global__ void fb_bn_final(const float* __restrict__ H,
                            const float* __restrict__ sum,
                            const float* __restrict__ sumsq,
                            const float* __restrict__ g,
                            const float* __restrict__ be,
                            float* __restrict__ out) {
  const int t = threadIdx.x;
  const int c0 = (t * 4) & (DIM - 1);
  const float invn = 1.f / (float)N_NODES;
  float4 s4 = *(const float4*)&sum[c0];
  float4 q4 = *(const float4*)&sumsq[c0];
  float4 g4 = *(const float4*)&g[c0];
  float4 b4 = *(const float4*)&be[c0];
  float scl[4], shf[4];
#pragma unroll
  for (int j = 0; j < 4; ++j) {
    const float mu = ((const float*)&s4)[j] * invn;
    const float var = ((const float*)&q4)[j] * invn - mu * mu;
    const float s = ((const float*)&g4)[j] * rsqrtf(var + 1e-5f);
    scl[j] = s;
    shf[j] = fmaf(-mu, s, ((const float*)&b4)[j]);
  }
  const int stride = gridDim.x * 256;
  for (int i = blockIdx.x * 256 + t; i < N_NODES * DIM / 4; i += stride) {
    const float4 h = ((const float4*)H)[i];
    float4 o;
    o.x = fmaxf(fmaf(h.x, scl[0], shf[0]), 0.f);
    o.y = fmaxf(fmaf(h.y, scl[1], shf[1]), 0.f);
    o.z = fmaxf(fmaf(h.z, scl[2], shf[2]), 0.f);
    o.w = fmaxf(fmaf(h.w, scl[3], shf[3]), 0.f);
    ((float4*)out)[i] = o;
  }
}

// ---------------------------------------------------------------------------
extern "C" void kernel_launch(void* const* d_in, const int* in_sizes, int n_in,
                              void* d_out, int out_size, void* d_ws, size_t ws_size,
                              hipStream_t stream) {
  const float* x   = (const float*)d_in[0];
  const int*   ei  = (const int*)d_in[1];   // int32 (JAX x64 disabled)
  const float* wq  = (const float*)d_in[2];
  const float* bq  = (const float*)d_in[3];
  const float* wk  = (const float*)d_in[4];
  const float* bk  = (const float*)d_in[5];
  const float* wv  = (const float*)d_in[6];
  const float* bv  = (const float*)d_in[7];
  const float* wo  = (const float*)d_in[8];
  const float* bo  = (const float*)d_in[9];
  const float* eps = (const float*)d_in[10];
  const float* w1  = (const float*)d_in[11];
  const float* b1  = (const float*)d_in[12];
  const float* g1  = (const float*)d_in[13];
  const float* be1 = (const float*)d_in[14];
  const float* w2  = (const float*)d_in[15];
  const float* b2  = (const float*)d_in[16];
  const float* g2  = (const float*)d_in[17];
  const float* be2 = (const float*)d_in[18];
  float* out = (float*)d_out;

  char* ws = (char*)d_ws;
  unsigned int* mask = (unsigned int*)ws;                          // 2 MB
  size_t off = (size_t)N_NODES * MWORDS * 4;
  short* wt_hi = (short*)(ws + off); off += (size_t)1536 * GK * 2;
  short* wt_lo = (short*)(ws + off); off += (size_t)1536 * GK * 2;
  float* bqkv  = (float*)(ws + off); off += 768 * 4;
  float* stats = (float*)(ws + off); off += 1024 * 4;
  off = (off + 255) & ~(size_t)255;
  float* qkv  = (float*)(ws + off); off += (size_t)N_NODES * 768 * 4;
  float* vagg = (float*)(ws + off); off += (size_t)N_NODES * DIM * 4;
  float* a1   = (float*)(ws + off); off += (size_t)N_NODES * DIM * 4;
  float* h1   = (float*)(ws + off); off += (size_t)N_NODES * DIM * 4;
  float* h2   = (float*)(ws + off); off += (size_t)N_NODES * DIM * 4;

  const int E = in_sizes[1] / 2;

  Params hp;
  hp.x = x; hp.ei = ei; hp.E = E;
  hp.wq = wq; hp.wk = wk; hp.wv = wv; hp.wo = wo; hp.w1 = w1; hp.w2 = w2;
  hp.bq = bq; hp.bk = bk; hp.bv = bv; hp.bo = bo; hp.b1 = b1; hp.b2 = b2;
  hp.g1 = g1; hp.be1 = be1; hp.g2 = g2; hp.be2 = be2;
  hp.eps = eps;
  hp.mask = mask; hp.wt_hi = wt_hi; hp.wt_lo = wt_lo;
  hp.bqkv = bqkv; hp.stats = stats;
  hp.qkv = qkv; hp.vagg = vagg; hp.a1 = a1; hp.h1 = h1; hp.h2 = h2;
  hp.out = out;

  void* args[] = {&hp};
  hipError_t err = hipLaunchCooperativeKernel((const void*)mega, dim3(MEGA_GRID),
                                              dim3(256), args, 0, stream);
  if (err == hipSuccess) return;
  (void)hipGetLastError();  // clear error state; use fallback path

  const int nmb = (E + 255) / 256;
  hipMemsetAsync(mask, 0, (size_t)N_NODES * MWORDS * 4, stream);
  fb_prep<<<nmb + 1537, 256, 0, stream>>>(ei, E, nmb, mask, wq, wk, wv, wo,
                                          w1, w2, bq, bk, bv, wt_hi, wt_lo,
                                          bqkv, stats);
  dim3 gq(768 / 64, N_NODES / 64);
  fb_gemm<0, false, false><<<gq, 256, 0, stream>>>(
      x, wt_hi, wt_lo, bqkv, qkv, 768,
      nullptr, nullptr, nullptr, nullptr, nullptr, nullptr, nullptr, nullptr);
  fb_attn<<<N_NODES / 4, 256, 0, stream>>>(qkv, mask, vagg);
  dim3 gg(DIM / 64, N_NODES / 64);
  fb_gemm<1, false, false><<<gg, 256, 0, stream>>>(
      vagg, wt_hi + (size_t)768 * GK, wt_lo + (size_t)768 * GK, bo, a1, DIM,
      x, eps, nullptr, nullptr, nullptr, nullptr, nullptr, nullptr);
  fb_gemm<0, false, true><<<gg, 256, 0, stream>>>(
      a1, wt_hi + (size_t)1024 * GK, wt_lo + (size_t)1024 * GK, b1, h1, DIM,
      nullptr, nullptr, nullptr, nullptr, nullptr, nullptr, stats, stats + 256);
  fb_gemm<2, true, true><<<gg, 256, 0, stream>>>(
      h1, wt_hi + (size_t)1280 * GK, wt_lo + (size_t)1280 * GK, b2, h2, DIM,
      nullptr, nullptr, stats, stats + 256, g1, be1, stats + 512, stats + 768);
  fb_bn_final<<<512, 256, 0, stream>>>(h2, stats + 512, stats + 768, g2, be2, out);
}

// Round 6
// 162.320 us; speedup vs baseline: 5.1942x; 5.1942x over previous
//
#include <hip/hip_runtime.h>
#include <math.h>

#define N_NODES 4096
#define DIM 256
#define GK 256
#define MWORDS 128
#define MAXNBR 192

typedef float f32x4 __attribute__((ext_vector_type(4)));
typedef short s16x8 __attribute__((ext_vector_type(8)));
typedef short s16x4 __attribute__((ext_vector_type(4)));

__device__ __forceinline__ unsigned short bf16_rne(float f) {
  unsigned int u = __float_as_uint(f);
  u += 0x7FFFu + ((u >> 16) & 1u);
  return (unsigned short)(u >> 16);
}

__device__ __forceinline__ void split_bf16(float f, short& hi, short& lo) {
  unsigned short h = bf16_rne(f);
  float hf = __uint_as_float(((unsigned int)h) << 16);
  hi = (short)h;
  lo = (short)bf16_rne(f - hf);
}

// LDS XOR swizzle for [64][64]-short tiles (pitch 64 shorts = 128B).
__device__ __forceinline__ int swz(int row, int col) {
  return row * 64 + (col ^ ((row & 7) << 3));
}

// ---------------------------------------------------------------------------
// GEMM core: C[m0:+64, n0:+64] = A[. ,256] @ Wt^T + bias.
// PRESPLIT: A arrives as bf16 hi/lo [M][256] (pure copy staging).
// EPI 0: bias. EPI 1: bias + ev*X. EPI 2 (PRESPLIT=false): A-side
//        a' = relu(a*bnsc[k]+bnsh[k]) applied during f32 staging.
// WRITE_C: store f32 C. SPLIT_OUT: store bf16 hi/lo of result.
// STATS_OUT: per-column sum/sumsq atomics.
// ---------------------------------------------------------------------------
template <int EPI, bool PRESPLIT, bool WRITE_C, bool SPLIT_OUT, bool STATS_OUT>
__device__ __forceinline__ void gemm_core(
    short* As_hi, short* As_lo, short* Bs_hi, short* Bs_lo, float* red,
    const float* bnsc, const float* bnsh,
    const float* __restrict__ Af, const short* __restrict__ A_hi,
    const short* __restrict__ A_lo,
    const short* __restrict__ Wt_hi, const short* __restrict__ Wt_lo,
    const float* __restrict__ bias, float* __restrict__ C, int ldc,
    short* __restrict__ C_hi, short* __restrict__ C_lo,
    int m0, int n0, const float* __restrict__ X, float ev,
    float* __restrict__ osum, float* __restrict__ osq) {
  const int tid = threadIdx.x;
  const int lane = tid & 63;
  const int wave = tid >> 6;
  const int wr = wave >> 1, wc = wave & 1;
  const int l15 = lane & 15;
  const int lg = lane >> 4;

  f32x4 acc[2][2] = {};

  for (int kt = 0; kt < GK; kt += 64) {
    __syncthreads();
    if (PRESPLIT) {
      // ---- stage A: pure bf16 copies, same pattern as B ----
#pragma unroll
      for (int i = 0; i < 2; ++i) {
        const int row = (tid >> 3) + i * 32;
        const int kc = (tid & 7) * 8;
        const size_t g = (size_t)(m0 + row) * GK + kt + kc;
        s16x8 ah = *(const s16x8*)(A_hi + g);
        s16x8 al = *(const s16x8*)(A_lo + g);
        const int o = swz(row, kc);
        *(s16x8*)&As_hi[o] = ah;
        *(s16x8*)&As_lo[o] = al;
      }
    } else {
      // ---- stage A: f32 -> (BN+ReLU) -> bf16 hi/lo split ----
#pragma unroll
      for (int i = 0; i < 4; ++i) {
        const int row = (tid >> 4) + i * 16;
        const int kc = (tid & 15) * 4;
        float4 av = *(const float4*)(Af + (size_t)(m0 + row) * GK + kt + kc);
        if (EPI == 2) {
          const float4 s4 = *(const float4*)&bnsc[kt + kc];
          const float4 h4 = *(const float4*)&bnsh[kt + kc];
          av.x = fmaxf(fmaf(av.x, s4.x, h4.x), 0.f);
          av.y = fmaxf(fmaf(av.y, s4.y, h4.y), 0.f);
          av.z = fmaxf(fmaf(av.z, s4.z, h4.z), 0.f);
          av.w = fmaxf(fmaf(av.w, s4.w, h4.w), 0.f);
        }
        short h0, l0, h1, l1, h2, l2, h3, l3;
        split_bf16(av.x, h0, l0);
        split_bf16(av.y, h1, l1);
        split_bf16(av.z, h2, l2);
        split_bf16(av.w, h3, l3);
        s16x4 hv = {h0, h1, h2, h3};
        s16x4 lv = {l0, l1, l2, l3};
        const int o = swz(row, kc);
        *(s16x4*)&As_hi[o] = hv;
        *(s16x4*)&As_lo[o] = lv;
      }
    }
    // ---- stage B ----
#pragma unroll
    for (int i = 0; i < 2; ++i) {
      const int row = (tid >> 3) + i * 32;
      const int kc = (tid & 7) * 8;
      const size_t g = (size_t)(n0 + row) * GK + kt + kc;
      s16x8 bh = *(const s16x8*)(Wt_hi + g);
      s16x8 bl = *(const s16x8*)(Wt_lo + g);
      const int o = swz(row, kc);
      *(s16x8*)&Bs_hi[o] = bh;
      *(s16x8*)&Bs_lo[o] = bl;
    }
    __syncthreads();
    // ---- MFMA: 2 k-chunks of 32, 2x2 fragments, 3 split terms ----
#pragma unroll
    for (int kk = 0; kk < 2; ++kk) {
      s16x8 ah[2], al[2], bh[2], bl[2];
#pragma unroll
      for (int f = 0; f < 2; ++f) {
        const int ao = swz(wr * 32 + f * 16 + l15, kk * 32 + lg * 8);
        const int bo = swz(wc * 32 + f * 16 + l15, kk * 32 + lg * 8);
        ah[f] = *(const s16x8*)&As_hi[ao];
        al[f] = *(const s16x8*)&As_lo[ao];
        bh[f] = *(const s16x8*)&Bs_hi[bo];
        bl[f] = *(const s16x8*)&Bs_lo[bo];
      }
#pragma unroll
      for (int fm = 0; fm < 2; ++fm)
#pragma unroll
        for (int fn = 0; fn < 2; ++fn) {
          acc[fm][fn] = __builtin_amdgcn_mfma_f32_16x16x32_bf16(ah[fm], bh[fn], acc[fm][fn], 0, 0, 0);
          acc[fm][fn] = __builtin_amdgcn_mfma_f32_16x16x32_bf16(ah[fm], bl[fn], acc[fm][fn], 0, 0, 0);
          acc[fm][fn] = __builtin_amdgcn_mfma_f32_16x16x32_bf16(al[fm], bh[fn], acc[fm][fn], 0, 0, 0);
        }
    }
  }

  // ---- epilogue: D layout col = lane&15, row = (lane>>4)*4 + reg ----
  float ps[2] = {0.f, 0.f}, pq[2] = {0.f, 0.f};
#pragma unroll
  for (int fm = 0; fm < 2; ++fm) {
    const int row0 = m0 + wr * 32 + fm * 16 + lg * 4;
#pragma unroll
    for (int fn = 0; fn < 2; ++fn) {
      const int col = n0 + wc * 32 + fn * 16 + l15;
      const float bb = bias[col];
#pragma unroll
      for (int j = 0; j < 4; ++j) {
        float v = acc[fm][fn][j] + bb;
        if (EPI == 1) v = fmaf(ev, X[(size_t)(row0 + j) * DIM + col], v);
        if (WRITE_C) C[(size_t)(row0 + j) * ldc + col] = v;
        if (SPLIT_OUT) {
          short hi, lo;
          split_bf16(v, hi, lo);
          C_hi[(size_t)(row0 + j) * DIM + col] = hi;
          C_lo[(size_t)(row0 + j) * DIM + col] = lo;
        }
        if (STATS_OUT) {
          ps[fn] += v;
          pq[fn] = fmaf(v, v, pq[fn]);
        }
      }
    }
  }
  if (STATS_OUT) {
    float* redS = red;
    float* redQ = red + 64;
#pragma unroll
    for (int fn = 0; fn < 2; ++fn) {
      ps[fn] += __shfl_xor(ps[fn], 16);
      ps[fn] += __shfl_xor(ps[fn], 32);
      pq[fn] += __shfl_xor(pq[fn], 16);
      pq[fn] += __shfl_xor(pq[fn], 32);
    }
    if (wr == 1 && lane < 16) {
      redS[(wc * 2 + 0) * 16 + l15] = ps[0];
      redS[(wc * 2 + 1) * 16 + l15] = ps[1];
      redQ[(wc * 2 + 0) * 16 + l15] = pq[0];
      redQ[(wc * 2 + 1) * 16 + l15] = pq[1];
    }
    __syncthreads();
    if (wr == 0 && lane < 16) {
#pragma unroll
      for (int fn = 0; fn < 2; ++fn) {
        const int col = n0 + wc * 32 + fn * 16 + l15;
        atomicAdd(&osum[col], ps[fn] + redS[(wc * 2 + fn) * 16 + l15]);
        atomicAdd(&osq[col], pq[fn] + redQ[(wc * 2 + fn) * 16 + l15]);
      }
    }
  }
}

// ---------------------------------------------------------------------------
// Prep: zero mask (all blocks) | transpose-split weights (96) | split x (512)
//       | zero stats (1) | pack bqkv (3). Grid = 1024 x 256.
// ---------------------------------------------------------------------------
__global__ __launch_bounds__(256) void k_prep(
    const float* __restrict__ x,
    const float* __restrict__ wq, const float* __restrict__ wk,
    const float* __restrict__ wv, const float* __restrict__ wo,
    const float* __restrict__ w1, const float* __restrict__ w2,
    const float* __restrict__ bq, const float* __restrict__ bk,
    const float* __restrict__ bv,
    unsigned int* __restrict__ mask, short* __restrict__ wt_hi,
    short* __restrict__ wt_lo, short* __restrict__ x_hi,
    short* __restrict__ x_lo, float* __restrict__ bqkv,
    float* __restrict__ stats) {
  __shared__ float tr[64][65];
  const int bid = blockIdx.x;
  const int tid = threadIdx.x;

  mask[bid * 512 + tid] = 0u;
  mask[bid * 512 + 256 + tid] = 0u;

  if (bid < 96) {  // weight split, coalesced both sides via LDS transpose
    const int mat = bid >> 4;
    const int tile = bid & 15;
    const int ti = tile >> 2;  // k block
    const int tj = tile & 3;   // n block
    const float* src = (mat == 0) ? wq : (mat == 1) ? wk : (mat == 2) ? wv
                     : (mat == 3) ? wo : (mat == 4) ? w1 : w2;
#pragma unroll
    for (int q = 0; q < 16; ++q) {
      const int r = q * 4 + (tid >> 6);
      tr[r][tid & 63] = src[(size_t)(ti * 64 + r) * 256 + tj * 64 + (tid & 63)];
    }
    __syncthreads();
    const int nbase = (mat < 3) ? mat * 256 : 768 + (mat - 3) * 256;
#pragma unroll
    for (int q = 0; q < 16; ++q) {
      const int n = q * 4 + (tid >> 6);
      const int k = tid & 63;
      short hi, lo;
      split_bf16(tr[k][n], hi, lo);
      const size_t idx = (size_t)(nbase + tj * 64 + n) * GK + ti * 64 + k;
      wt_hi[idx] = hi;
      wt_lo[idx] = lo;
    }
  } else if (bid < 608) {  // x split: 8 rows per block, coalesced
    const int r0 = (bid - 96) * 8;
#pragma unroll
    for (int r = 0; r < 8; ++r) {
      const size_t g = (size_t)(r0 + r) * 256 + tid;
      short hi, lo;
      split_bf16(x[g], hi, lo);
      x_hi[g] = hi;
      x_lo[g] = lo;
    }
  } else if (bid == 608) {
    stats[tid] = 0.f;
    stats[tid + 256] = 0.f;
    stats[tid + 512] = 0.f;
    stats[tid + 768] = 0.f;
  } else if (bid >= 609 && bid < 612) {
    const int mat = bid - 609;
    bqkv[mat * 256 + tid] = (mat == 0 ? bq : mat == 1 ? bk : bv)[tid];
  }
}

// ---------------------------------------------------------------------------
// QKV GEMM (+ edge scatter riding along): [4096,256]@[256,768] -> qkv f32.
// Grid: (12, 64). Edge block index = by*12+bx, 176 edges each.
// ---------------------------------------------------------------------------
__global__ __launch_bounds__(256) void k_qkv(
    const short* __restrict__ x_hi, const short* __restrict__ x_lo,
    const short* __restrict__ wt_hi, const short* __restrict__ wt_lo,
    const float* __restrict__ bqkv, float* __restrict__ qkv,
    const int* __restrict__ ei, int E, unsigned int* __restrict__ mask) {
  __shared__ __align__(16) short As_hi[4096], As_lo[4096], Bs_hi[4096], Bs_lo[4096];
  // edge scatter first; atomics drain under the GEMM
  {
    const int blin = blockIdx.y * 12 + blockIdx.x;
    const int epb = (E + 767) / 768;
    const int e = blin * epb + threadIdx.x;
    if (threadIdx.x < epb && e < E) {
      const int r = ei[e];
      const int c = ei[E + e];
      atomicOr(&mask[(size_t)r * MWORDS + (c >> 5)], 1u << (c & 31));
    }
  }
  gemm_core<0, true, true, false, false>(
      As_hi, As_lo, Bs_hi, Bs_lo, nullptr, nullptr, nullptr,
      nullptr, x_hi, x_lo, wt_hi, wt_lo, bqkv, qkv, 768, nullptr, nullptr,
      blockIdx.y * 64, blockIdx.x * 64, nullptr, 0.f, nullptr, nullptr);
}

// ---------------------------------------------------------------------------
// Sparse attention, 1 wave per row; batch-8 gathers; emits vagg as bf16 hi/lo.
// ---------------------------------------------------------------------------
__global__ __launch_bounds__(256) void k_attn(
    const float* __restrict__ qkv, const unsigned int* __restrict__ mask,
    short* __restrict__ vagg_hi, short* __restrict__ vagg_lo) {
  __shared__ int nbr[4][MAXNBR];
  const int wave = threadIdx.x >> 6;
  const int lane = threadIdx.x & 63;
  const int r = blockIdx.x * 4 + wave;

  const unsigned int* mrow = mask + (size_t)r * MWORDS;
  int total = 0;
#pragma unroll
  for (int round = 0; round < 2; ++round) {
    unsigned int w = mrow[round * 64 + lane];
    const int cnt = __popc(w);
    int pre = cnt;
#pragma unroll
    for (int off = 1; off < 64; off <<= 1) {
      int tt = __shfl_up(pre, off);
      if (lane >= off) pre += tt;
    }
    const int wtot = __shfl(pre, 63);
    pre -= cnt;
    int base = total + pre;
    while (w) {
      const int b = __ffs(w) - 1;
      w &= w - 1;
      nbr[wave][base++] = (round * 64 + lane) * 32 + b;
    }
    total += wtot;
  }

  float4 q = *(const float4*)(qkv + (size_t)r * 768 + lane * 4);
  const float sc = 0.088388347648318447f;  // 1/sqrt(128)
  q.x *= sc; q.y *= sc; q.z *= sc; q.w *= sc;
  float4 acc = make_float4(0.f, 0.f, 0.f, 0.f);
  float m = -INFINITY, lsum = 0.f;
  const int* nb = nbr[wave];

  for (int i = 0; i < total; i += 8) {
    int cs[8];
    float4 kf[8], vf[8];
    float d[8];
#pragma unroll
    for (int j = 0; j < 8; ++j) cs[j] = (i + j < total) ? nb[i + j] : -1;
#pragma unroll
    for (int j = 0; j < 8; ++j) {
      const float* pp = qkv + (size_t)(cs[j] < 0 ? cs[0] : cs[j]) * 768 + lane * 4;
      kf[j] = *(const float4*)(pp + 256);
      vf[j] = *(const float4*)(pp + 512);
    }
#pragma unroll
    for (int j = 0; j < 8; ++j)
      d[j] = q.x * kf[j].x + q.y * kf[j].y + q.z * kf[j].z + q.w * kf[j].w;
#pragma unroll
    for (int s = 16; s >= 1; s >>= 1)
#pragma unroll
      for (int j = 0; j < 8; ++j) d[j] += __shfl_xor(d[j], s);
#pragma unroll
    for (int j = 1; j < 8; ++j)
      if (cs[j] < 0) d[j] = -INFINITY;
    float mnew = m;
#pragma unroll
    for (int j = 0; j < 8; ++j) mnew = fmaxf(mnew, d[j]);
    const float resc = __expf(m - mnew);
    float e[8], esum = 0.f;
#pragma unroll
    for (int j = 0; j < 8; ++j) {
      e[j] = __expf(d[j] - mnew);
      esum += e[j];
    }
    lsum = lsum * resc + esum;
    float ax = acc.x * resc, ay = acc.y * resc, az = acc.z * resc, aw = acc.w * resc;
#pragma unroll
    for (int j = 0; j < 8; ++j) {
      ax = fmaf(e[j], vf[j].x, ax);
      ay = fmaf(e[j], vf[j].y, ay);
      az = fmaf(e[j], vf[j].z, az);
      aw = fmaf(e[j], vf[j].w, aw);
    }
    acc.x = ax; acc.y = ay; acc.z = az; acc.w = aw;
    m = mnew;
  }
  const float inv = 1.f / lsum;
  const float o[4] = {acc.x * inv, acc.y * inv, acc.z * inv, acc.w * inv};
  short hs[4], ls[4];
#pragma unroll
  for (int j = 0; j < 4; ++j) split_bf16(o[j], hs[j], ls[j]);
  const size_t g = (size_t)r * DIM + lane * 4;
  *(s16x4*)(vagg_hi + g) = *(s16x4*)hs;
  *(s16x4*)(vagg_lo + g) = *(s16x4*)ls;
}

// ---------------------------------------------------------------------------
// proj: vagg @ wo + bo + eps*x -> a1 (bf16 hi/lo only, no f32 store).
// ---------------------------------------------------------------------------
__global__ __launch_bounds__(256) void k_proj(
    const short* __restrict__ vagg_hi, const short* __restrict__ vagg_lo,
    const short* __restrict__ wt_hi, const short* __restrict__ wt_lo,
    const float* __restrict__ bo, const float* __restrict__ x,
    const float* __restrict__ epsp,
    short* __restrict__ a1_hi, short* __restrict__ a1_lo) {
  __shared__ __align__(16) short As_hi[4096], As_lo[4096], Bs_hi[4096], Bs_lo[4096];
  gemm_core<1, true, false, true, false>(
      As_hi, As_lo, Bs_hi, Bs_lo, nullptr, nullptr, nullptr,
      nullptr, vagg_hi, vagg_lo, wt_hi, wt_lo, bo, nullptr, DIM, a1_hi, a1_lo,
      blockIdx.y * 64, blockIdx.x * 64, x, epsp[0], nullptr, nullptr);
}

// ---------------------------------------------------------------------------
// mlp1: a1 @ w1 + b1 -> h1 f32 + BN1 stats.
// ---------------------------------------------------------------------------
__global__ __launch_bounds__(256) void k_mlp1(
    const short* __restrict__ a1_hi, const short* __restrict__ a1_lo,
    const short* __restrict__ wt_hi, const short* __restrict__ wt_lo,
    const float* __restrict__ b1, float* __restrict__ h1,
    float* __restrict__ osum, float* __restrict__ osq) {
  __shared__ __align__(16) short As_hi[4096], As_lo[4096], Bs_hi[4096], Bs_lo[4096];
  __shared__ float red[128];
  gemm_core<0, true, true, false, true>(
      As_hi, As_lo, Bs_hi, Bs_lo, red, nullptr, nullptr,
      nullptr, a1_hi, a1_lo, wt_hi, wt_lo, b1, h1, DIM, nullptr, nullptr,
      blockIdx.y * 64, blockIdx.x * 64, nullptr, 0.f, osum, osq);
}

// ---------------------------------------------------------------------------
// mlp2: relu(BN1(h1)) @ w2 + b2 -> h2 f32 + BN2 stats. BN1 finalized inline.
// ---------------------------------------------------------------------------
__global__ __launch_bounds__(256) void k_mlp2(
    const float* __restrict__ h1,
    const short* __restrict__ wt_hi, const short* __restrict__ wt_lo,
    const float* __restrict__ b2,
    const float* __restrict__ bnsum, const float* __restrict__ bnsq,
    const float* __restrict__ g1, const float* __restrict__ be1,
    float* __restrict__ h2, float* __restrict__ osum, float* __restrict__ osq) {
  __shared__ __align__(16) short As_hi[4096], As_lo[4096], Bs_hi[4096], Bs_lo[4096];
  __shared__ __align__(16) float bnsc[256], bnsh[256];
  __shared__ float red[128];
  const int tid = threadIdx.x;
  {
    const float invn = 1.f / (float)N_NODES;
    const float mu = bnsum[tid] * invn;
    const float var = bnsq[tid] * invn - mu * mu;
    const float s = g1[tid] * rsqrtf(var + 1e-5f);
    bnsc[tid] = s;
    bnsh[tid] = fmaf(-mu, s, be1[tid]);
  }
  gemm_core<2, false, true, false, true>(
      As_hi, As_lo, Bs_hi, Bs_lo, red, bnsc, bnsh,
      h1, nullptr, nullptr, wt_hi, wt_lo, b2, h2, DIM, nullptr, nullptr,
      blockIdx.y * 64, blockIdx.x * 64, nullptr, 0.f, osum, osq);
}

// ---------------------------------------------------------------------------
// BN2 finalize + apply + ReLU -> out.
// ---------------------------------------------------------------------------
__global__ __launch_bounds__(256) void k_bnfinal(
    const float* __restrict__ H, const float* __restrict__ sum,
    const float* __restrict__ sumsq, const float* __restrict__ g,
    const float* __restrict__ be, float* __restrict__ out) {
  const int t = threadIdx.x;
  const int c0 = (t * 4) & (DIM - 1);
  const float invn = 1.f / (float)N_NODES;
  float4 s4 = *(const float4*)&sum[c0];
  float4 q4 = *(const float4*)&sumsq[c0];
  float4 g4 = *(const float4*)&g[c0];
  float4 b4 = *(const float4*)&be[c0];
  float scl[4], shf[4];
#pragma unroll
  for (int j = 0; j < 4; ++j) {
    const float mu = ((const float*)&s4)[j] * invn;
    const float var = ((const float*)&q4)[j] * invn - mu * mu;
    const float s = ((const float*)&g4)[j] * rsqrtf(var + 1e-5f);
    scl[j] = s;
    shf[j] = fmaf(-mu, s, ((const float*)&b4)[j]);
  }
  const int stride = gridDim.x * 256;
  for (int i = blockIdx.x * 256 + t; i < N_NODES * DIM / 4; i += stride) {
    const float4 h = ((const float4*)H)[i];
    float4 o;
    o.x = fmaxf(fmaf(h.x, scl[0], shf[0]), 0.f);
    o.y = fmaxf(fmaf(h.y, scl[1], shf[1]), 0.f);
    o.z = fmaxf(fmaf(h.z, scl[2], shf[2]), 0.f);
    o.w = fmaxf(fmaf(h.w, scl[3], shf[3]), 0.f);
    ((float4*)out)[i] = o;
  }
}

// ---------------------------------------------------------------------------
extern "C" void kernel_launch(void* const* d_in, const int* in_sizes, int n_in,
                              void* d_out, int out_size, void* d_ws, size_t ws_size,
                              hipStream_t stream) {
  const float* x   = (const float*)d_in[0];
  const int*   ei  = (const int*)d_in[1];   // int32 (JAX x64 disabled)
  const float* wq  = (const float*)d_in[2];
  const float* bq  = (const float*)d_in[3];
  const float* wk  = (const float*)d_in[4];
  const float* bk  = (const float*)d_in[5];
  const float* wv  = (const float*)d_in[6];
  const float* bv  = (const float*)d_in[7];
  const float* wo  = (const float*)d_in[8];
  const float* bo  = (const float*)d_in[9];
  const float* eps = (const float*)d_in[10];
  const float* w1  = (const float*)d_in[11];
  const float* b1  = (const float*)d_in[12];
  const float* g1  = (const float*)d_in[13];
  const float* be1 = (const float*)d_in[14];
  const float* w2  = (const float*)d_in[15];
  const float* b2  = (const float*)d_in[16];
  const float* g2  = (const float*)d_in[17];
  const float* be2 = (const float*)d_in[18];
  float* out = (float*)d_out;

  char* ws = (char*)d_ws;
  unsigned int* mask = (unsigned int*)ws;                            // 2 MB
  size_t off = (size_t)N_NODES * MWORDS * 4;
  short* wt_hi = (short*)(ws + off); off += (size_t)1536 * GK * 2;
  short* wt_lo = (short*)(ws + off); off += (size_t)1536 * GK * 2;
  short* x_hi  = (short*)(ws + off); off += (size_t)N_NODES * DIM * 2;
  short* x_lo  = (short*)(ws + off); off += (size_t)N_NODES * DIM * 2;
  short* vg_hi = (short*)(ws + off); off += (size_t)N_NODES * DIM * 2;
  short* vg_lo = (short*)(ws + off); off += (size_t)N_NODES * DIM * 2;
  short* a1_hi = (short*)(ws + off); off += (size_t)N_NODES * DIM * 2;
  short* a1_lo = (short*)(ws + off); off += (size_t)N_NODES * DIM * 2;
  float* bqkv  = (float*)(ws + off); off += 768 * 4;
  float* stats = (float*)(ws + off); off += 1024 * 4;
  off = (off + 255) & ~(size_t)255;
  float* qkv = (float*)(ws + off); off += (size_t)N_NODES * 768 * 4;  // 12 MB
  float* h1  = (float*)(ws + off); off += (size_t)N_NODES * DIM * 4;
  float* h2  = (float*)(ws + off); off += (size_t)N_NODES * DIM * 4;

  const int E = in_sizes[1] / 2;

  k_prep<<<1024, 256, 0, stream>>>(x, wq, wk, wv, wo, w1, w2, bq, bk, bv,
                                   mask, wt_hi, wt_lo, x_hi, x_lo, bqkv, stats);
  k_qkv<<<dim3(12, 64), 256, 0, stream>>>(x_hi, x_lo, wt_hi, wt_lo, bqkv, qkv,
                                          ei, E, mask);
  k_attn<<<N_NODES / 4, 256, 0, stream>>>(qkv, mask, vg_hi, vg_lo);
  k_proj<<<dim3(4, 64), 256, 0, stream>>>(vg_hi, vg_lo,
                                          wt_hi + (size_t)768 * GK,
                                          wt_lo + (size_t)768 * GK,
                                          bo, x, eps, a1_hi, a1_lo);
  k_mlp1<<<dim3(4, 64), 256, 0, stream>>>(a1_hi, a1_lo,
                                          wt_hi + (size_t)1024 * GK,
                                          wt_lo + (size_t)1024 * GK,
                                          b1, h1, stats, stats + 256);
  k_mlp2<<<dim3(4, 64), 256, 0, stream>>>(h1,
                                          wt_hi + (size_t)1280 * GK,
                                          wt_lo + (size_t)1280 * GK,
                                          b2, stats, stats + 256, g1, be1,
                                          h2, stats + 512, stats + 768);
  k_bnfinal<<<512, 256, 0, stream>>>(h2, stats + 512, stats + 768, g2, be2, out);
}

// Round 8
// 158.864 us; speedup vs baseline: 5.3071x; 1.0218x over previous
//
#include <hip/hip_runtime.h>
#include <math.h>

#define N_NODES 4096
#define DIM 256
#define GK 256
#define MWORDS 128
#define MAXNBR 192

typedef float f32x4 __attribute__((ext_vector_type(4)));
typedef short s16x8 __attribute__((ext_vector_type(8)));
typedef short s16x4 __attribute__((ext_vector_type(4)));

__device__ __forceinline__ unsigned short bf16_rne(float f) {
  unsigned int u = __float_as_uint(f);
  u += 0x7FFFu + ((u >> 16) & 1u);
  return (unsigned short)(u >> 16);
}

__device__ __forceinline__ float bf2f(unsigned short u) {
  return __uint_as_float(((unsigned int)u) << 16);
}

__device__ __forceinline__ void split_bf16(float f, short& hi, short& lo) {
  unsigned short h = bf16_rne(f);
  float hf = __uint_as_float(((unsigned int)h) << 16);
  hi = (short)h;
  lo = (short)bf16_rne(f - hf);
}

// LDS XOR swizzle, pitch 64 shorts (128 B); valid for row in [0,64).
__device__ __forceinline__ int swz(int row, int col) {
  return row * 64 + (col ^ ((row & 7) << 3));
}

// ---------------------------------------------------------------------------
// GEMM core, 32x64 tile, 4 waves (wave = 16-col group), bf16 hi/lo 3-term.
// EPI 0: bias. 1: bias + ev*X. 2: A-side a'=relu(a*bnsc+bnsh) (f32 staging).
// OUT 0: f32 C. 1: bf16 hi/lo C. 2: QKV triple (f32 Q | bf16 K | bf16 V).
// STATS_OUT: per-column sum/sumsq atomics (one atomic per col per block).
// ---------------------------------------------------------------------------
template <int EPI, bool PRESPLIT, int OUT, bool STATS_OUT>
__device__ __forceinline__ void gemm_core(
    short* As_hi, short* As_lo, short* Bs_hi, short* Bs_lo,
    const float* bnsc, const float* bnsh,
    const float* __restrict__ Af, const short* __restrict__ A_hi,
    const short* __restrict__ A_lo,
    const short* __restrict__ Wt_hi, const short* __restrict__ Wt_lo,
    const float* __restrict__ bias,
    float* __restrict__ C, short* __restrict__ C_hi, short* __restrict__ C_lo,
    float* __restrict__ qf, unsigned short* __restrict__ kb,
    unsigned short* __restrict__ vb,
    int m0, int n0, const float* __restrict__ X, float ev,
    float* __restrict__ osum, float* __restrict__ osq) {
  const int tid = threadIdx.x;
  const int lane = tid & 63;
  const int wc = tid >> 6;       // 0..3: 16-col group
  const int l15 = lane & 15;
  const int lg = lane >> 4;      // 0..3: row quarter

  f32x4 acc[2] = {};

  for (int kt = 0; kt < GK; kt += 64) {
    __syncthreads();
    // ---- stage A (32 rows x 64 k) ----
    {
      const int row = tid >> 3;
      const int kc = (tid & 7) * 8;
      if (PRESPLIT) {
        const size_t g = (size_t)(m0 + row) * GK + kt + kc;
        *(s16x8*)&As_hi[swz(row, kc)] = *(const s16x8*)(A_hi + g);
        *(s16x8*)&As_lo[swz(row, kc)] = *(const s16x8*)(A_lo + g);
      } else {
        const float* src = Af + (size_t)(m0 + row) * GK + kt + kc;
        float a[8];
        *(float4*)&a[0] = *(const float4*)src;
        *(float4*)&a[4] = *(const float4*)(src + 4);
        if (EPI == 2) {
#pragma unroll
          for (int i = 0; i < 8; ++i)
            a[i] = fmaxf(fmaf(a[i], bnsc[kt + kc + i], bnsh[kt + kc + i]), 0.f);
        }
        short h[8], l[8];
#pragma unroll
        for (int i = 0; i < 8; ++i) split_bf16(a[i], h[i], l[i]);
        *(s16x8*)&As_hi[swz(row, kc)] = *(const s16x8*)h;
        *(s16x8*)&As_lo[swz(row, kc)] = *(const s16x8*)l;
      }
    }
    // ---- stage B (64 rows x 64 k) ----
#pragma unroll
    for (int i = 0; i < 2; ++i) {
      const int row = (tid >> 3) + i * 32;
      const int kc = (tid & 7) * 8;
      const size_t g = (size_t)(n0 + row) * GK + kt + kc;
      *(s16x8*)&Bs_hi[swz(row, kc)] = *(const s16x8*)(Wt_hi + g);
      *(s16x8*)&Bs_lo[swz(row, kc)] = *(const s16x8*)(Wt_lo + g);
    }
    __syncthreads();
    // ---- MFMA ----
#pragma unroll
    for (int kk = 0; kk < 2; ++kk) {
      s16x8 ah[2], al[2];
#pragma unroll
      for (int f = 0; f < 2; ++f) {
        const int ao = swz(f * 16 + l15, kk * 32 + lg * 8);
        ah[f] = *(const s16x8*)&As_hi[ao];
        al[f] = *(const s16x8*)&As_lo[ao];
      }
      const int bo_ = swz(wc * 16 + l15, kk * 32 + lg * 8);
      const s16x8 bh = *(const s16x8*)&Bs_hi[bo_];
      const s16x8 bl = *(const s16x8*)&Bs_lo[bo_];
#pragma unroll
      for (int f = 0; f < 2; ++f) {
        acc[f] = __builtin_amdgcn_mfma_f32_16x16x32_bf16(ah[f], bh, acc[f], 0, 0, 0);
        acc[f] = __builtin_amdgcn_mfma_f32_16x16x32_bf16(ah[f], bl, acc[f], 0, 0, 0);
        acc[f] = __builtin_amdgcn_mfma_f32_16x16x32_bf16(al[f], bh, acc[f], 0, 0, 0);
      }
    }
  }

  // ---- epilogue: D col = lane&15 (+16*wc), row = lg*4 + j (+16*fm) ----
  const int col = n0 + wc * 16 + l15;
  const float bb = bias[col];
  float ps = 0.f, pq = 0.f;
#pragma unroll
  for (int fm = 0; fm < 2; ++fm) {
    const int row0 = m0 + fm * 16 + lg * 4;
#pragma unroll
    for (int j = 0; j < 4; ++j) {
      const int row = row0 + j;
      float v = acc[fm][j] + bb;
      if (EPI == 1) v = fmaf(ev, X[(size_t)row * DIM + col], v);
      if (OUT == 0) C[(size_t)row * DIM + col] = v;
      if (OUT == 1) {
        short hi, lo;
        split_bf16(v, hi, lo);
        C_hi[(size_t)row * DIM + col] = hi;
        C_lo[(size_t)row * DIM + col] = lo;
      }
      if (OUT == 2) {
        if (n0 < 256) qf[(size_t)row * DIM + col] = v;
        else if (n0 < 512) kb[(size_t)row * DIM + col - 256] = bf16_rne(v);
        else vb[(size_t)row * DIM + col - 512] = bf16_rne(v);
      }
      if (STATS_OUT) {
        ps += v;
        pq = fmaf(v, v, pq);
      }
    }
  }
  if (STATS_OUT) {
    ps += __shfl_xor(ps, 16);
    ps += __shfl_xor(ps, 32);
    pq += __shfl_xor(pq, 16);
    pq += __shfl_xor(pq, 32);
    if (lane < 16) {
      atomicAdd(&osum[col], ps);
      atomicAdd(&osq[col], pq);
    }
  }
}

// ---------------------------------------------------------------------------
// Prep: zero mask | transpose-split weights (96 blk) | split x (512 blk) |
//       zero stats | pack bqkv. Grid 1024 x 256.
// ---------------------------------------------------------------------------
__global__ __launch_bounds__(256) void k_prep(
    const float* __restrict__ x,
    const float* __restrict__ wq, const float* __restrict__ wk,
    const float* __restrict__ wv, const float* __restrict__ wo,
    const float* __restrict__ w1, const float* __restrict__ w2,
    const float* __restrict__ bq, const float* __restrict__ bk,
    const float* __restrict__ bv,
    unsigned int* __restrict__ mask, short* __restrict__ wt_hi,
    short* __restrict__ wt_lo, short* __restrict__ x_hi,
    short* __restrict__ x_lo, float* __restrict__ bqkv,
    float* __restrict__ stats) {
  __shared__ float tr[64][65];
  const int bid = blockIdx.x;
  const int tid = threadIdx.x;

  mask[bid * 512 + tid] = 0u;
  mask[bid * 512 + 256 + tid] = 0u;

  if (bid < 96) {
    const int mat = bid >> 4;
    const int tile = bid & 15;
    const int ti = tile >> 2;
    const int tj = tile & 3;
    const float* src = (mat == 0) ? wq : (mat == 1) ? wk : (mat == 2) ? wv
                     : (mat == 3) ? wo : (mat == 4) ? w1 : w2;
#pragma unroll
    for (int q = 0; q < 16; ++q) {
      const int r = q * 4 + (tid >> 6);
      tr[r][tid & 63] = src[(size_t)(ti * 64 + r) * 256 + tj * 64 + (tid & 63)];
    }
    __syncthreads();
    const int nbase = (mat < 3) ? mat * 256 : 768 + (mat - 3) * 256;
#pragma unroll
    for (int q = 0; q < 16; ++q) {
      const int n = q * 4 + (tid >> 6);
      const int k = tid & 63;
      short hi, lo;
      split_bf16(tr[k][n], hi, lo);
      const size_t idx = (size_t)(nbase + tj * 64 + n) * GK + ti * 64 + k;
      wt_hi[idx] = hi;
      wt_lo[idx] = lo;
    }
  } else if (bid < 608) {
    const int r0 = (bid - 96) * 8;
#pragma unroll
    for (int r = 0; r < 8; ++r) {
      const size_t g = (size_t)(r0 + r) * 256 + tid;
      short hi, lo;
      split_bf16(x[g], hi, lo);
      x_hi[g] = hi;
      x_lo[g] = lo;
    }
  } else if (bid == 608) {
    stats[tid] = 0.f;
    stats[tid + 256] = 0.f;
    stats[tid + 512] = 0.f;
    stats[tid + 768] = 0.f;
  } else if (bid >= 609 && bid < 612) {
    const int mat = bid - 609;
    bqkv[mat * 256 + tid] = (mat == 0 ? bq : mat == 1 ? bk : bv)[tid];
  }
}

// ---------------------------------------------------------------------------
// QKV GEMM + edge scatter. Grid (12, 128). Writes Q f32, K/V bf16.
// ---------------------------------------------------------------------------
__global__ __launch_bounds__(256) void k_qkv(
    const short* __restrict__ x_hi, const short* __restrict__ x_lo,
    const short* __restrict__ wt_hi, const short* __restrict__ wt_lo,
    const float* __restrict__ bqkv, float* __restrict__ qf,
    unsigned short* __restrict__ kb, unsigned short* __restrict__ vb,
    const int* __restrict__ ei, int E, unsigned int* __restrict__ mask) {
  __shared__ __align__(16) short As_hi[2048], As_lo[2048], Bs_hi[4096], Bs_lo[4096];
  {
    const int blin = blockIdx.y * 12 + blockIdx.x;
    const int epb = (E + 1535) / 1536;
    const int e = blin * epb + threadIdx.x;
    if (threadIdx.x < epb && e < E) {
      const int r = ei[e];
      const int c = ei[E + e];
      atomicOr(&mask[(size_t)r * MWORDS + (c >> 5)], 1u << (c & 31));
    }
  }
  gemm_core<0, true, 2, false>(
      As_hi, As_lo, Bs_hi, Bs_lo, nullptr, nullptr,
      nullptr, x_hi, x_lo, wt_hi, wt_lo, bqkv,
      nullptr, nullptr, nullptr, qf, kb, vb,
      blockIdx.y * 32, blockIdx.x * 64, nullptr, 0.f, nullptr, nullptr);
}

// ---------------------------------------------------------------------------
// Sparse attention: 1 wave / row, batch-8 gathers, Q f32 + K/V bf16.
// ---------------------------------------------------------------------------
__global__ __launch_bounds__(256) void k_attn(
    const float* __restrict__ qf, const unsigned short* __restrict__ kb,
    const unsigned short* __restrict__ vb, const unsigned int* __restrict__ mask,
    short* __restrict__ vagg_hi, short* __restrict__ vagg_lo) {
  __shared__ int nbr[4][MAXNBR];
  const int wave = threadIdx.x >> 6;
  const int lane = threadIdx.x & 63;
  const int r = blockIdx.x * 4 + wave;

  const unsigned int* mrow = mask + (size_t)r * MWORDS;
  int total = 0;
#pragma unroll
  for (int round = 0; round < 2; ++round) {
    unsigned int w = mrow[round * 64 + lane];
    const int cnt = __popc(w);
    int pre = cnt;
#pragma unroll
    for (int off = 1; off < 64; off <<= 1) {
      int tt = __shfl_up(pre, off);
      if (lane >= off) pre += tt;
    }
    const int wtot = __shfl(pre, 63);
    pre -= cnt;
    int base = total + pre;
    while (w) {
      const int b = __ffs(w) - 1;
      w &= w - 1;
      nbr[wave][base++] = (round * 64 + lane) * 32 + b;
    }
    total += wtot;
  }

  float4 q = *(const float4*)(qf + (size_t)r * DIM + lane * 4);
  const float sc = 0.088388347648318447f;  // 1/sqrt(128)
  q.x *= sc; q.y *= sc; q.z *= sc; q.w *= sc;
  float4 acc = make_float4(0.f, 0.f, 0.f, 0.f);
  float m = -INFINITY, lsum = 0.f;
  const int* nb = nbr[wave];

  for (int i = 0; i < total; i += 8) {
    int cs[8];
    ushort4 ku[8], vu[8];
    float d[8];
#pragma unroll
    for (int j = 0; j < 8; ++j) cs[j] = (i + j < total) ? nb[i + j] : -1;
#pragma unroll
    for (int j = 0; j < 8; ++j) {
      const size_t g = (size_t)(cs[j] < 0 ? cs[0] : cs[j]) * DIM + lane * 4;
      ku[j] = *(const ushort4*)(kb + g);
      vu[j] = *(const ushort4*)(vb + g);
    }
#pragma unroll
    for (int j = 0; j < 8; ++j)
      d[j] = q.x * bf2f(ku[j].x) + q.y * bf2f(ku[j].y) +
             q.z * bf2f(ku[j].z) + q.w * bf2f(ku[j].w);
#pragma unroll
    for (int s = 16; s >= 1; s >>= 1)
#pragma unroll
      for (int j = 0; j < 8; ++j) d[j] += __shfl_xor(d[j], s);
#pragma unroll
    for (int j = 1; j < 8; ++j)
      if (cs[j] < 0) d[j] = -INFINITY;
    float mnew = m;
#pragma unroll
    for (int j = 0; j < 8; ++j) mnew = fmaxf(mnew, d[j]);
    const float resc = __expf(m - mnew);
    float e[8], esum = 0.f;
#pragma unroll
    for (int j = 0; j < 8; ++j) {
      e[j] = __expf(d[j] - mnew);
      esum += e[j];
    }
    lsum = lsum * resc + esum;
    float ax = acc.x * resc, ay = acc.y * resc, az = acc.z * resc, aw = acc.w * resc;
#pragma unroll
    for (int j = 0; j < 8; ++j) {
      ax = fmaf(e[j], bf2f(vu[j].x), ax);
      ay = fmaf(e[j], bf2f(vu[j].y), ay);
      az = fmaf(e[j], bf2f(vu[j].z), az);
      aw = fmaf(e[j], bf2f(vu[j].w), aw);
    }
    acc.x = ax; acc.y = ay; acc.z = az; acc.w = aw;
    m = mnew;
  }
  const float inv = 1.f / lsum;
  const float o[4] = {acc.x * inv, acc.y * inv, acc.z * inv, acc.w * inv};
  short hs[4], ls[4];
#pragma unroll
  for (int j = 0; j < 4; ++j) split_bf16(o[j], hs[j], ls[j]);
  const size_t g = (size_t)r * DIM + lane * 4;
  *(s16x4*)(vagg_hi + g) = *(s16x4*)hs;
  *(s16x4*)(vagg_lo + g) = *(s16x4*)ls;
}

// ---------------------------------------------------------------------------
__global__ __launch_bounds__(256) void k_proj(
    const short* __restrict__ vagg_hi, const short* __restrict__ vagg_lo,
    const short* __restrict__ wt_hi, const short* __restrict__ wt_lo,
    const float* __restrict__ bo, const float* __restrict__ x,
    const float* __restrict__ epsp,
    short* __restrict__ a1_hi, short* __restrict__ a1_lo) {
  __shared__ __align__(16) short As_hi[2048], As_lo[2048], Bs_hi[4096], Bs_lo[4096];
  gemm_core<1, true, 1, false>(
      As_hi, As_lo, Bs_hi, Bs_lo, nullptr, nullptr,
      nullptr, vagg_hi, vagg_lo, wt_hi, wt_lo, bo,
      nullptr, a1_hi, a1_lo, nullptr, nullptr, nullptr,
      blockIdx.y * 32, blockIdx.x * 64, x, epsp[0], nullptr, nullptr);
}

__global__ __launch_bounds__(256) void k_mlp1(
    const short* __restrict__ a1_hi, const short* __restrict__ a1_lo,
    const short* __restrict__ wt_hi, const short* __restrict__ wt_lo,
    const float* __restrict__ b1, float* __restrict__ h1,
    float* __restrict__ osum, float* __restrict__ osq) {
  __shared__ __align__(16) short As_hi[2048], As_lo[2048], Bs_hi[4096], Bs_lo[4096];
  gemm_core<0, true, 0, true>(
      As_hi, As_lo, Bs_hi, Bs_lo, nullptr, nullptr,
      nullptr, a1_hi, a1_lo, wt_hi, wt_lo, b1,
      h1, nullptr, nullptr, nullptr, nullptr, nullptr,
      blockIdx.y * 32, blockIdx.x * 64, nullptr, 0.f, osum, osq);
}

__global__ __launch_bounds__(256) void k_mlp2(
    const float* __restrict__ h1,
    const short* __restrict__ wt_hi, const short* __restrict__ wt_lo,
    const float* __restrict__ b2,
    const float* __restrict__ bnsum, const float* __restrict__ bnsq,
    const float* __restrict__ g1, const float* __restrict__ be1,
    float* __restrict__ h2, float* __restrict__ osum, float* __restrict__ osq) {
  __shared__ __align__(16) short As_hi[2048], As_lo[2048], Bs_hi[4096], Bs_lo[4096];
  __shared__ __align__(16) float bnsc[256], bnsh[256];
  const int tid = threadIdx.x;
  {
    const float invn = 1.f / (float)N_NODES;
    const float mu = bnsum[tid] * invn;
    const float var = bnsq[tid] * invn - mu * mu;
    const float s = g1[tid] * rsqrtf(var + 1e-5f);
    bnsc[tid] = s;
    bnsh[tid] = fmaf(-mu, s, be1[tid]);
  }
  gemm_core<2, false, 0, true>(
      As_hi, As_lo, Bs_hi, Bs_lo, bnsc, bnsh,
      h1, nullptr, nullptr, wt_hi, wt_lo, b2,
      h2, nullptr, nullptr, nullptr, nullptr, nullptr,
      blockIdx.y * 32, blockIdx.x * 64, nullptr, 0.f, osum, osq);
}

__global__ __launch_bounds__(256) void k_bnfinal(
    const float* __restrict__ H, const float* __restrict__ sum,
    const float* __restrict__ sumsq, const float* __restrict__ g,
    const float* __restrict__ be, float* __restrict__ out) {
  const int t = threadIdx.x;
  const int c0 = (t * 4) & (DIM - 1);
  const float invn = 1.f / (float)N_NODES;
  float4 s4 = *(const float4*)&sum[c0];
  float4 q4 = *(const float4*)&sumsq[c0];
  float4 g4 = *(const float4*)&g[c0];
  float4 b4 = *(const float4*)&be[c0];
  float scl[4], shf[4];
#pragma unroll
  for (int j = 0; j < 4; ++j) {
    const float mu = ((const float*)&s4)[j] * invn;
    const float var = ((const float*)&q4)[j] * invn - mu * mu;
    const float s = ((const float*)&g4)[j] * rsqrtf(var + 1e-5f);
    scl[j] = s;
    shf[j] = fmaf(-mu, s, ((const float*)&b4)[j]);
  }
  const int stride = gridDim.x * 256;
  for (int i = blockIdx.x * 256 + t; i < N_NODES * DIM / 4; i += stride) {
    const float4 h = ((const float4*)H)[i];
    float4 o;
    o.x = fmaxf(fmaf(h.x, scl[0], shf[0]), 0.f);
    o.y = fmaxf(fmaf(h.y, scl[1], shf[1]), 0.f);
    o.z = fmaxf(fmaf(h.z, scl[2], shf[2]), 0.f);
    o.w = fmaxf(fmaf(h.w, scl[3], shf[3]), 0.f);
    ((float4*)out)[i] = o;
  }
}

// ---------------------------------------------------------------------------
extern "C" void kernel_launch(void* const* d_in, const int* in_sizes, int n_in,
                              void* d_out, int out_size, void* d_ws, size_t ws_size,
                              hipStream_t stream) {
  const float* x   = (const float*)d_in[0];
  const int*   ei  = (const int*)d_in[1];   // int32 (JAX x64 disabled)
  const float* wq  = (const float*)d_in[2];
  const float* bq  = (const float*)d_in[3];
  const float* wk  = (const float*)d_in[4];
  const float* bk  = (const float*)d_in[5];
  const float* wv  = (const float*)d_in[6];
  const float* bv  = (const float*)d_in[7];
  const float* wo  = (const float*)d_in[8];
  const float* bo  = (const float*)d_in[9];
  const float* eps = (const float*)d_in[10];
  const float* w1  = (const float*)d_in[11];
  const float* b1  = (const float*)d_in[12];
  const float* g1  = (const float*)d_in[13];
  const float* be1 = (const float*)d_in[14];
  const float* w2  = (const float*)d_in[15];
  const float* b2  = (const float*)d_in[16];
  const float* g2  = (const float*)d_in[17];
  const float* be2 = (const float*)d_in[18];
  float* out = (float*)d_out;

  char* ws = (char*)d_ws;
  unsigned int* mask = (unsigned int*)ws;                            // 2 MB
  size_t off = (size_t)N_NODES * MWORDS * 4;
  short* wt_hi = (short*)(ws + off); off += (size_t)1536 * GK * 2;
  short* wt_lo = (short*)(ws + off); off += (size_t)1536 * GK * 2;
  short* x_hi  = (short*)(ws + off); off += (size_t)N_NODES * DIM * 2;
  short* x_lo  = (short*)(ws + off); off += (size_t)N_NODES * DIM * 2;
  short* vg_hi = (short*)(ws + off); off += (size_t)N_NODES * DIM * 2;
  short* vg_lo = (short*)(ws + off); off += (size_t)N_NODES * DIM * 2;
  short* a1_hi = (short*)(ws + off); off += (size_t)N_NODES * DIM * 2;
  short* a1_lo = (short*)(ws + off); off += (size_t)N_NODES * DIM * 2;
  unsigned short* kb = (unsigned short*)(ws + off); off += (size_t)N_NODES * DIM * 2;
  unsigned short* vb = (unsigned short*)(ws + off); off += (size_t)N_NODES * DIM * 2;
  float* bqkv  = (float*)(ws + off); off += 768 * 4;
  float* stats = (float*)(ws + off); off += 1024 * 4;
  off = (off + 255) & ~(size_t)255;
  float* qf = (float*)(ws + off); off += (size_t)N_NODES * DIM * 4;
  float* h1 = (float*)(ws + off); off += (size_t)N_NODES * DIM * 4;
  float* h2 = (float*)(ws + off); off += (size_t)N_NODES * DIM * 4;

  const int E = in_sizes[1] / 2;

  k_prep<<<1024, 256, 0, stream>>>(x, wq, wk, wv, wo, w1, w2, bq, bk, bv,
                                   mask, wt_hi, wt_lo, x_hi, x_lo, bqkv, stats);
  k_qkv<<<dim3(12, 128), 256, 0, stream>>>(x_hi, x_lo, wt_hi, wt_lo, bqkv,
                                           qf, kb, vb, ei, E, mask);
  k_attn<<<N_NODES / 4, 256, 0, stream>>>(qf, kb, vb, mask, vg_hi, vg_lo);
  k_proj<<<dim3(4, 128), 256, 0, stream>>>(vg_hi, vg_lo,
                                           wt_hi + (size_t)768 * GK,
                                           wt_lo + (size_t)768 * GK,
                                           bo, x, eps, a1_hi, a1_lo);
  k_mlp1<<<dim3(4, 128), 256, 0, stream>>>(a1_hi, a1_lo,
                                           wt_hi + (size_t)1024 * GK,
                                           wt_lo + (size_t)1024 * GK,
                                           b1, h1, stats, stats + 256);
  k_mlp2<<<dim3(4, 128), 256, 0, stream>>>(h1,
                                           wt_hi + (size_t)1280 * GK,
                                           wt_lo + (size_t)1280 * GK,
                                           b2, stats, stats + 256, g1, be1,
                                           h2, stats + 512, stats + 768);
  k_bnfinal<<<512, 256, 0, stream>>>(h2, stats + 512, stats + 768, g2, be2, out);
}